// Round 7
// baseline (967.303 us; speedup 1.0000x reference)
//
#include <hip/hip_runtime.h>
#include <math.h>

#define NCLS 19      // known classes (void = 19 dropped)
#define NF   256     // feature length
#define HW   16384   // 128*128 pixels per image
#define NB   16      // batch
#define PX   (NB*HW) // 262144 total pixels
#define C2   (HW/2)  // channel stride in float2

// ================= PROBES (read-only, no output; liveness via asm) =================

// P1: m13-replica grid-stride streaming read, 3 passes over all 256MB.
// If healthy: ~120-160us total (invisible in top-5). If capped at ~750GB/s: ~1000us.
__global__ __launch_bounds__(256) void probe_gridstride(const float4* __restrict__ f4) {
    const size_t n4 = 16777216;               // 67,108,864 floats / 4
    const size_t stride = (size_t)4096 * 256; // grid*block
    float s = 0.f;
    size_t idx = (size_t)blockIdx.x * 256 + threadIdx.x;
    for (int pass = 0; pass < 3; ++pass) {
        for (size_t i = idx; i < n4; i += stride) {
            float4 v = f4[i];
            s += v.x + v.y + v.z + v.w;
        }
    }
    asm volatile("" :: "v"(s));
}

// P3: R4's exact load pattern (64KB-stride float2, 16-deep batch, 512x256),
// with all LDS/atomic work stripped. One pass over 256MB.
// Fast (~100-130us) => loads fine, R4's cost was elsewhere. Slow (~450-550us) => pattern.
__global__ __launch_bounds__(256) void probe_stride64k(const float* __restrict__ feat) {
    const int tid = threadIdx.x;
    const int r   = tid >> 6;
    const int w0  = (tid & 63) * 2;
    const int row = blockIdx.x * 4 + r;
    const int b   = row >> 7;
    const int h   = row & 127;

    const float2* p = (const float2*)(feat + ((size_t)b * NF * HW + (size_t)h * 128 + w0));
    float s0 = 0.f, s1 = 0.f;
    for (int f = 0; f < NF; f += 16) {
        float2 v[16];
        #pragma unroll
        for (int u = 0; u < 16; ++u) v[u] = p[(size_t)(f + u) * C2];
        #pragma unroll
        for (int u = 0; u < 16; ++u) {
            s0 += v[u].x * v[u].x;
            s1 += v[u].y * v[u].y;
        }
    }
    asm volatile("" :: "v"(s0), "v"(s1));
}

// ================= PIPELINE (identical to R6, known-correct) =================

__global__ __launch_bounds__(256) void zero_ws(float* __restrict__ nrm2,
                                               float* __restrict__ gproto) {
    int i = blockIdx.x * 256 + threadIdx.x;
    if (i < PX) nrm2[i] = 0.f;
    if (i < NCLS * NF) gproto[i] = 0.f;
}

__global__ __launch_bounds__(1024) void sumsq_kernel(const float* __restrict__ feat,
                                                     float* __restrict__ nrm2) {
    const int g  = blockIdx.x;
    const int b  = g >> 5;
    const int f0 = (g & 31) << 3;
    const int t  = threadIdx.x;

    const float* base = feat + (size_t)(b * NF + f0) * HW + t * 4;
    float* np = nrm2 + b * HW + t * 4;

    for (int k = 0; k < 4; ++k) {
        float4 v[8];
        #pragma unroll
        for (int s = 0; s < 8; ++s)
            v[s] = *(const float4*)(base + (size_t)s * HW + k * 4096);
        float a0 = 0.f, a1 = 0.f, a2 = 0.f, a3 = 0.f;
        #pragma unroll
        for (int s = 0; s < 8; ++s) {
            a0 += v[s].x * v[s].x;
            a1 += v[s].y * v[s].y;
            a2 += v[s].z * v[s].z;
            a3 += v[s].w * v[s].w;
        }
        atomicAdd(&np[k * 4096 + 0], a0);
        atomicAdd(&np[k * 4096 + 1], a1);
        atomicAdd(&np[k * 4096 + 2], a2);
        atomicAdd(&np[k * 4096 + 3], a3);
    }
}

__global__ __launch_bounds__(256) void rinv_kernel(float* __restrict__ nrm2) {
    int i = (blockIdx.x * 256 + threadIdx.x) * 4;
    float4 s = *(float4*)(nrm2 + i);
    float4 r;
    r.x = 1.f / fmaxf(sqrtf(s.x), 1e-12f);
    r.y = 1.f / fmaxf(sqrtf(s.y), 1e-12f);
    r.z = 1.f / fmaxf(sqrtf(s.z), 1e-12f);
    r.w = 1.f / fmaxf(sqrtf(s.w), 1e-12f);
    *(float4*)(nrm2 + i) = r;
}

__global__ __launch_bounds__(1024) void scatter_kernel(const float* __restrict__ feat,
                                                       const int* __restrict__ labels,
                                                       const float* __restrict__ rinv,
                                                       float* __restrict__ gproto) {
    __shared__ float lp[NCLS * 9];
    const int t = threadIdx.x;
    if (t < NCLS * 9) lp[t] = 0.f;
    __syncthreads();

    const int g  = blockIdx.x;
    const int b  = g >> 5;
    const int f0 = (g & 31) << 3;

    const float* base = feat + (size_t)(b * NF + f0) * HW + t * 4;
    const int*   lb   = labels + b * HW + t * 4;
    const float* rv   = rinv   + b * HW + t * 4;

    for (int k = 0; k < 4; ++k) {
        const int4   l4 = *(const int4*)(lb + k * 4096);
        const float4 r4 = *(const float4*)(rv + k * 4096);
        float4 v[8];
        #pragma unroll
        for (int s = 0; s < 8; ++s)
            v[s] = *(const float4*)(base + (size_t)s * HW + k * 4096);
        #pragma unroll
        for (int s = 0; s < 8; ++s) {
            if (l4.x < NCLS) atomicAdd(&lp[l4.x * 9 + s], v[s].x * r4.x);
            if (l4.y < NCLS) atomicAdd(&lp[l4.y * 9 + s], v[s].y * r4.y);
            if (l4.z < NCLS) atomicAdd(&lp[l4.z * 9 + s], v[s].z * r4.z);
            if (l4.w < NCLS) atomicAdd(&lp[l4.w * 9 + s], v[s].w * r4.w);
        }
    }
    __syncthreads();

    if (t < NCLS * 8) {
        const int c = t >> 3, fr = t & 7;
        const float val = lp[c * 9 + fr];
        if (val != 0.f) atomicAdd(&gproto[c * NF + f0 + fr], val);
    }
}

__global__ __launch_bounds__(256) void normalize_protos(const float* __restrict__ gproto,
                                                        float* __restrict__ out) {
    __shared__ float ws[4];
    const int c = blockIdx.x;
    const int f = threadIdx.x;
    const float v = gproto[c * NF + f];

    float s = v * v;
    #pragma unroll
    for (int off = 32; off > 0; off >>= 1) s += __shfl_down(s, off, 64);
    if ((f & 63) == 0) ws[f >> 6] = s;
    __syncthreads();
    const float tot = ws[0] + ws[1] + ws[2] + ws[3];
    const float rn = 1.f / fmaxf(sqrtf(tot), 1e-12f);
    out[f * NCLS + c] = v * rn;
}

extern "C" void kernel_launch(void* const* d_in, const int* in_sizes, int n_in,
                              void* d_out, int out_size, void* d_ws, size_t ws_size,
                              hipStream_t stream) {
    const float* feat   = (const float*)d_in[0];
    const int*   labels = (const int*)d_in[1];
    float* out    = (float*)d_out;
    float* gproto = (float*)d_ws;              // 4864 floats (slot of 8192)
    float* nrm2   = (float*)d_ws + 8192;       // 262144 floats (1 MB)

    // --- probes (read-only) ---
    probe_gridstride<<<4096, 256, 0, stream>>>((const float4*)feat);
    probe_stride64k<<<512, 256, 0, stream>>>(feat);

    // --- pipeline (R6) ---
    zero_ws<<<PX / 256, 256, 0, stream>>>(nrm2, gproto);
    sumsq_kernel<<<512, 1024, 0, stream>>>(feat, nrm2);
    rinv_kernel<<<PX / 1024, 256, 0, stream>>>(nrm2);
    scatter_kernel<<<512, 1024, 0, stream>>>(feat, labels, nrm2, gproto);
    normalize_protos<<<NCLS, 256, 0, stream>>>(gproto, out);
}